// Round 4
// baseline (358.297 us; speedup 1.0000x reference)
//
#include <hip/hip_runtime.h>

#define B_ 32
#define T_ 2048
#define H_ 256
#define L_ 2049   // T_ + 1
#define ZCUT 512
#define ZROWS (L_ - ZCUT)            // 1537 zero rows per batch (training)
#define FOLD_BLKS 16

// ---------------- helpers ----------------
__device__ inline double waveReduceD(double v) {
#pragma unroll
  for (int off = 32; off > 0; off >>= 1) v += __shfl_xor(v, off, 64);
  return v;
}

typedef float vfloat4 __attribute__((ext_vector_type(4)));
__device__ inline void nt_store4(float4 v, float* p) {
  vfloat4 t;
  t.x = v.x; t.y = v.y; t.z = v.z; t.w = v.w;
  __builtin_nontemporal_store(t, (vfloat4*)p);
}

// device-scope grid barrier. Arrive = ONE fetch_add per block (acq_rel,
// agent scope). Poll = read-only acquire load + s_sleep backoff — no RMW
// contention (round-3's atomicAdd(cnt,0) poll serialized 1024 RMWs at the
// coherent point -> ~100us/barrier). Counters on separate cache lines.
__device__ inline void gridbar(int* cnt, int idx, int nblk) {
  __syncthreads();
  if (threadIdx.x == 0) {
    int* c = cnt + idx * 32;             // 128B apart
    __threadfence();                     // release our writes (L2 wb on CDNA)
    int arrived = __hip_atomic_fetch_add(c, 1, __ATOMIC_ACQ_REL,
                                         __HIP_MEMORY_SCOPE_AGENT) + 1;
    if (arrived < nblk) {
      while (__hip_atomic_load(c, __ATOMIC_ACQUIRE,
                               __HIP_MEMORY_SCOPE_AGENT) < nblk)
        __builtin_amdgcn_s_sleep(16);    // ~0.4us backoff
    }
    __threadfence();                     // acquire others' writes
  }
  __syncthreads();
}

// =====================================================================
// Fused resident kernel: phase0 (fold + zero-fill) -> bar -> phase1 (dots)
// -> bar -> phase2 (weights/fire solve, 32 blocks) -> bar -> phase3 (cif rows)
// =====================================================================
__global__ void __launch_bounds__(256, 2) k_fused(
    const float* __restrict__ x, const float* __restrict__ mask,
    const float* __restrict__ W1, const float* __restrict__ b1,
    const float* __restrict__ W2, const float* __restrict__ b2,
    const int* __restrict__ is_tr,
    float* __restrict__ o_cif, float* __restrict__ o_ori,
    float* __restrict__ o_ff, float* __restrict__ o_np,
    float* __restrict__ o_sa,
    double* __restrict__ vd, double* __restrict__ c0p,
    double* __restrict__ d1, double* __restrict__ d2,
    float* __restrict__ absS, float* __restrict__ wsc,
    int* __restrict__ fireT, int* __restrict__ nAllArr,
    int* __restrict__ nUnmArr, int* __restrict__ bar) {
  __shared__ double s_P[T_];        // 16 KB: phase0 scratch alias + phase2 P
  __shared__ double s_tot[4];
  __shared__ double s_red[4][3];
  __shared__ double s_tot2[4];
  __shared__ double s_mtot[4];
  __shared__ int s_int[2];

  int bid = blockIdx.x, tid = threadIdx.x;
  int wave = tid >> 6, lane = tid & 63;
  int nblk = gridDim.x;
  int training = is_tr[0];

  // ---------------- phase 0: fold (blocks 0..15) + zero-fill tail ----------
  if (bid < FOLD_BLKS) {
    double* s_p = s_P;               // [8][32] -> 256 doubles
    int cl = tid & 31, sl = tid >> 5;
    int c = bid * 32 + cl;
    double acc = 0.0;
#pragma unroll 8
    for (int o = sl * 64; o < sl * 64 + 64; ++o)
      acc += (double)W2[o] * (double)W1[o * 512 + c];
    s_p[sl * 32 + cl] = acc;
    __syncthreads();
    if (sl == 0) {
      double v = 0.0;
#pragma unroll
      for (int i = 0; i < 8; ++i) v += s_p[i * 32 + cl];
      vd[c] = v;
    }
    if (bid == 0) {
      double* red = s_P + 256;       // disjoint from s_p region
      double p = (double)W2[tid] * (double)b1[tid] +
                 (double)W2[tid + 256] * (double)b1[tid + 256];
      red[tid] = p;
      __syncthreads();
      for (int s = 128; s > 0; s >>= 1) {
        if (tid < s) red[tid] += red[tid + s];
        __syncthreads();
      }
      if (tid == 0) c0p[0] = red[0] + (double)b2[0];
    }
  } else if (training) {
    // zero-fill cif rows pos in [ZCUT, L) — provably zero when training
    // (sum of scaled weights = maskSum-1 <= 199 => nA << ZCUT).
    int i0 = (bid - FOLD_BLKS) * 4 + wave;
    int stride = (nblk - FOLD_BLKS) * 4;
    float4 z = make_float4(0.0f, 0.0f, 0.0f, 0.0f);
    for (int i = i0; i < B_ * ZROWS; i += stride) {
      int b = i / ZROWS, pos = ZCUT + (i - b * ZROWS);
      nt_store4(z, o_cif + ((long)b * L_ + pos) * H_ + lane * 4);
      if (lane == 0) o_np[(long)b * L_ + pos] = 0.0f;
    }
  }
  gridbar(bar, 0, nblk);

  // ---------------- phase 1: per-row dots (grid-stride over 4096 groups) ---
  for (int g = bid; g < (B_ * T_) / 16; g += nblk) {
    long row0 = ((long)g * 4 + wave) * 4;  // 4 consecutive rows per wave
    const float4* xr = (const float4*)(x + row0 * H_);
    float4 x0 = xr[lane];
    float4 x1 = xr[lane + 64];
    float4 x2 = xr[lane + 128];
    float4 x3 = xr[lane + 192];
    int base = lane * 4;
    double vb0 = vd[256 + base + 0], vb1 = vd[256 + base + 1],
           vb2 = vd[256 + base + 2], vb3 = vd[256 + base + 3];
    double va0 = vd[base + 0] + vb0, va1 = vd[base + 1] + vb1,
           va2 = vd[base + 2] + vb2, va3 = vd[base + 3] + vb3;
    double p10 = (double)x0.x * va0 + (double)x0.y * va1 + (double)x0.z * va2 + (double)x0.w * va3;
    double p20 = (double)x0.x * vb0 + (double)x0.y * vb1 + (double)x0.z * vb2 + (double)x0.w * vb3;
    double p11 = (double)x1.x * va0 + (double)x1.y * va1 + (double)x1.z * va2 + (double)x1.w * va3;
    double p21 = (double)x1.x * vb0 + (double)x1.y * vb1 + (double)x1.z * vb2 + (double)x1.w * vb3;
    double p12 = (double)x2.x * va0 + (double)x2.y * va1 + (double)x2.z * va2 + (double)x2.w * va3;
    double p22 = (double)x2.x * vb0 + (double)x2.y * vb1 + (double)x2.z * vb2 + (double)x2.w * vb3;
    double p13 = (double)x3.x * va0 + (double)x3.y * va1 + (double)x3.z * va2 + (double)x3.w * va3;
    double p23 = (double)x3.x * vb0 + (double)x3.y * vb1 + (double)x3.z * vb2 + (double)x3.w * vb3;
    bool n0 = (x0.x != 0.0f) || (x0.y != 0.0f) || (x0.z != 0.0f) || (x0.w != 0.0f);
    bool n1 = (x1.x != 0.0f) || (x1.y != 0.0f) || (x1.z != 0.0f) || (x1.w != 0.0f);
    bool n2 = (x2.x != 0.0f) || (x2.y != 0.0f) || (x2.z != 0.0f) || (x2.w != 0.0f);
    bool n3 = (x3.x != 0.0f) || (x3.y != 0.0f) || (x3.z != 0.0f) || (x3.w != 0.0f);
    unsigned long long bb0 = __ballot(n0), bb1 = __ballot(n1),
                       bb2 = __ballot(n2), bb3 = __ballot(n3);
#pragma unroll
    for (int off = 32; off > 0; off >>= 1) {
      p10 += __shfl_xor(p10, off, 64);
      p20 += __shfl_xor(p20, off, 64);
      p11 += __shfl_xor(p11, off, 64);
      p21 += __shfl_xor(p21, off, 64);
      p12 += __shfl_xor(p12, off, 64);
      p22 += __shfl_xor(p22, off, 64);
      p13 += __shfl_xor(p13, off, 64);
      p23 += __shfl_xor(p23, off, 64);
    }
    if (lane == 0)       { d1[row0 + 0] = p10; d2[row0 + 0] = p20; absS[row0 + 0] = bb0 ? 1.0f : 0.0f; }
    else if (lane == 16) { d1[row0 + 1] = p11; d2[row0 + 1] = p21; absS[row0 + 1] = bb1 ? 1.0f : 0.0f; }
    else if (lane == 32) { d1[row0 + 2] = p12; d2[row0 + 2] = p22; absS[row0 + 2] = bb2 ? 1.0f : 0.0f; }
    else if (lane == 48) { d1[row0 + 3] = p13; d2[row0 + 3] = p23; absS[row0 + 3] = bb3 ? 1.0f : 0.0f; }
  }
  gridbar(bar, 1, nblk);

  // ---------------- phase 2: weights + exact fire solve (blocks 0..31) -----
  if (bid < B_) {
    int b = bid;
    int lane_ = lane, wv = wave;
    int t0 = tid * 8;
    const double* d1b = d1 + (long)b * T_;
    const double* d2b = d2 + (long)b * T_;
    const float* asb = absS + (long)b * T_;
    double c0 = c0p[0];

    // prefix sum of d2 -> s_P
    double r2[8];
    {
      double run2 = 0.0;
#pragma unroll
      for (int k = 0; k < 8; ++k) { run2 += d2b[t0 + k]; r2[k] = run2; }
      double sc2 = run2;
#pragma unroll
      for (int off = 1; off < 64; off <<= 1) {
        double n = __shfl_up(sc2, off, 64);
        if (lane_ >= off) sc2 += n;
      }
      if (lane_ == 63) s_tot[wv] = sc2;
      __syncthreads();
      double base2 = 0.0;
      for (int i = 0; i < wv; ++i) base2 += s_tot[i];
      double e2 = base2 + (sc2 - run2);
#pragma unroll
      for (int k = 0; k < 8; ++k) s_P[t0 + k] = e2 + r2[k];
    }
    __syncthreads();

    // w = clip(relu(d1 - windowmean + c0), 0, 1)
    double wd[8];
    double sa = 0.0, fpc = 0.0;
#pragma unroll
    for (int k = 0; k < 8; ++k) {
      int t = t0 + k;
      double wvv;
      if (t == 0) {
        wvv = d1b[0] - s_P[0] + c0;
      } else {
        int start = t - 10; if (start < 0) start = 0;
        double ws_ = s_P[t - 1] - (start > 0 ? s_P[start - 1] : 0.0);
        wvv = d1b[t] - ws_ / (double)(t - start) + c0;
      }
      wvv = wvv < 0.0 ? 0.0 : (wvv > 1.0 ? 1.0 : wvv);
      wd[k] = wvv;
      sa += wvv;
      fpc += (asb[t] != 0.0f) ? 1.0 : 0.0;
    }
    {
      float4* ov = (float4*)(o_ori + (long)b * T_ + t0);
      ov[0] = make_float4((float)wd[0], (float)wd[1], (float)wd[2], (float)wd[3]);
      ov[1] = make_float4((float)wd[4], (float)wd[5], (float)wd[6], (float)wd[7]);
    }
    double ms = (tid < 200) ? (double)mask[(long)b * 200 + tid] : 0.0;
    double sar = waveReduceD(sa), fpr = waveReduceD(fpc), msr = waveReduceD(ms);
    if (lane_ == 0) { s_red[wv][0] = sar; s_red[wv][1] = fpr; s_red[wv][2] = msr; }
    __syncthreads();
    double sumA = s_red[0][0] + s_red[1][0] + s_red[2][0] + s_red[3][0];
    double fpD  = s_red[0][1] + s_red[1][1] + s_red[2][1] + s_red[3][1];
    double maskSum = s_red[0][2] + s_red[1][2] + s_red[2][2] + s_red[3][2];
    if (tid == 0) o_sa[b] = (float)sumA;
    int firstPad = (int)(fpD + 0.5);
    double scale;
    if (training != 0) {
      scale = (sumA == 0.0) ? 0.0 : (maskSum - 1.0) / (sumA > 1e-8 ? sumA : 1e-8);
    } else {
      scale = 1.0;
    }

    double a[8], r[8];
    double run = 0.0;
#pragma unroll
    for (int k = 0; k < 8; ++k) {
      int t = t0 + k;
      double av = wd[k] * scale;
      if (t > firstPad) av = 0.0;
      a[k] = av;
      run += av; r[k] = run;
    }
    {
      float4* wvv = (float4*)(wsc + (long)b * T_ + t0);
      wvv[0] = make_float4((float)a[0], (float)a[1], (float)a[2], (float)a[3]);
      wvv[1] = make_float4((float)a[4], (float)a[5], (float)a[6], (float)a[7]);
    }
    double sc = run;
#pragma unroll
    for (int off = 1; off < 64; off <<= 1) {
      double n = __shfl_up(sc, off, 64);
      if (lane_ >= off) sc += n;
    }
    if (lane_ == 63) s_tot2[wv] = sc;
    __syncthreads();
    double base = 0.0;
    for (int i = 0; i < wv; ++i) base += s_tot2[i];
    double e = base + (sc - run);

    double m[8];
    double mn = 1e300;
#pragma unroll
    for (int k = 0; k < 8; ++k) {
      double S = e + r[k];
      double kp = ceil(S - 1.0); if (kp < 0.0) kp = 0.0;
      double D = kp - (double)(t0 + k);
      mn = fmin(mn, D);
      m[k] = mn;
    }
    double scm = mn;
#pragma unroll
    for (int off = 1; off < 64; off <<= 1) {
      double n = __shfl_up(scm, off, 64);
      if (lane_ >= off) scm = fmin(scm, n);
    }
    double exw = __shfl_up(scm, 1, 64);
    if (lane_ == 0) exw = 1e300;
    if (lane_ == 63) s_mtot[wv] = scm;
    __syncthreads();
    double mbase = 1e300;
    for (int i = 0; i < wv; ++i) mbase = fmin(mbase, s_mtot[i]);
    double Mexcl = fmin(mbase, exw);

    float flags[8];
    int Cp = (t0 - 1) + (int)fmin(1.0, Mexcl);
#pragma unroll
    for (int k = 0; k < 8; ++k) {
      int t = t0 + k;
      double Mk = fmin(Mexcl, m[k]);
      int C = t + (int)fmin(1.0, Mk);
      bool fired = C > Cp;
      flags[k] = fired ? 1.0f : 0.0f;
      if (fired) fireT[(long)b * T_ + (C - 1)] = t;
      if (t == firstPad) s_int[0] = C;
      Cp = C;
    }
    {
      float4* fv = (float4*)(o_ff + (long)b * T_ + t0);
      fv[0] = make_float4(flags[0], flags[1], flags[2], flags[3]);
      fv[1] = make_float4(flags[4], flags[5], flags[6], flags[7]);
    }
    if (tid == 255) s_int[1] = Cp;
    __syncthreads();
    if (tid == 0) {
      int nA = s_int[1];
      nAllArr[b] = nA;
      nUnmArr[b] = (firstPad >= T_) ? nA : s_int[0];
    }
  }
  gridbar(bar, 2, nblk);

  // ---------------- phase 3: cif rows (one pos per wave, grid-stride) ------
  // training: only pos < ZCUT (rest pre-zeroed in phase 0); else all L rows.
  int total = training ? (B_ * ZCUT) : (B_ * L_);
  float4 z4 = make_float4(0.0f, 0.0f, 0.0f, 0.0f);
  for (int i = bid * 4 + wave; i < total; i += nblk * 4) {
    int b, pos;
    if (training) { b = i >> 9; pos = i & (ZCUT - 1); }
    else          { b = i / L_; pos = i - b * L_; }
    int nA = nAllArr[b], nU = nUnmArr[b];
    float* crow = o_cif + ((long)b * L_ + pos) * H_ + lane * 4;
    if (pos > nU) {
      nt_store4(z4, crow);
      if (lane == 0) o_np[(long)b * L_ + pos] = 0.0f;
      continue;
    }
    const int* ftb = fireT + (long)b * T_;
    int hi, anchor, lo;
    if (pos < nU) {
      hi = ftb[pos];
      anchor = (pos == 0) ? 0 : ftb[pos - 1];
      lo = (pos == 0) ? 0 : anchor + 1;
    } else {
      hi = T_ - 1;
      anchor = (nA == 0) ? 0 : ftb[nA - 1];
      lo = (nA == 0) ? 0 : anchor + 1;
    }
    const float* xb = x + (long)b * T_ * H_;
    float4 acc = ((const float4*)(xb + (long)anchor * H_))[lane];
    float4 acc2 = make_float4(0.0f, 0.0f, 0.0f, 0.0f);
    const float* wb = wsc + (long)b * T_;
    int u = lo;
    for (; u + 1 <= hi; u += 2) {
      float f0 = 1.0f - wb[u];
      float f1 = 1.0f - wb[u + 1];
      float4 xv0 = ((const float4*)(xb + (long)u * H_))[lane];
      float4 xv1 = ((const float4*)(xb + (long)(u + 1) * H_))[lane];
      acc.x += f0 * xv0.x;  acc.y += f0 * xv0.y;
      acc.z += f0 * xv0.z;  acc.w += f0 * xv0.w;
      acc2.x += f1 * xv1.x; acc2.y += f1 * xv1.y;
      acc2.z += f1 * xv1.z; acc2.w += f1 * xv1.w;
    }
    if (u <= hi) {
      float f = 1.0f - wb[u];
      float4 xv = ((const float4*)(xb + (long)u * H_))[lane];
      acc.x += f * xv.x; acc.y += f * xv.y; acc.z += f * xv.z; acc.w += f * xv.w;
    }
    acc.x += acc2.x; acc.y += acc2.y; acc.z += acc2.z; acc.w += acc2.w;
    float ss = acc.x * acc.x + acc.y * acc.y + acc.z * acc.z + acc.w * acc.w;
#pragma unroll
    for (int off = 32; off > 0; off >>= 1) ss += __shfl_xor(ss, off, 64);
    float inv = 1.0f / fmaxf(sqrtf(ss), 1e-12f);
    nt_store4(make_float4(acc.x * inv, acc.y * inv, acc.z * inv, acc.w * inv), crow);
    if (lane == 0) o_np[(long)b * L_ + pos] = 1.0f;
  }
}

// =====================================================================
// Fallback pipeline (round-1 verified kernels) — used only if the fused
// kernel cannot be made fully resident on this device.
// =====================================================================
__global__ void __launch_bounds__(256) k0_fold(
    const float* __restrict__ W1, const float* __restrict__ b1,
    const float* __restrict__ W2, const float* __restrict__ b2,
    double* __restrict__ vd, double* __restrict__ c0) {
  __shared__ double s_p[8][32];
  int tid = threadIdx.x;
  int cl = tid & 31, sl = tid >> 5;
  int c = blockIdx.x * 32 + cl;
  double acc = 0.0;
#pragma unroll 8
  for (int o = sl * 64; o < sl * 64 + 64; ++o)
    acc += (double)W2[o] * (double)W1[o * 512 + c];
  s_p[sl][cl] = acc;
  __syncthreads();
  if (sl == 0) {
    double v = 0.0;
#pragma unroll
    for (int i = 0; i < 8; ++i) v += s_p[i][cl];
    vd[c] = v;
  }
  if (blockIdx.x == 0) {
    __shared__ double red[256];
    double p = (double)W2[tid] * (double)b1[tid] +
               (double)W2[tid + 256] * (double)b1[tid + 256];
    red[tid] = p;
    __syncthreads();
    for (int s = 128; s > 0; s >>= 1) {
      if (tid < s) red[tid] += red[tid + s];
      __syncthreads();
    }
    if (tid == 0) c0[0] = red[0] + (double)b2[0];
  }
}

__global__ void __launch_bounds__(256) k1_rowdots(
    const float* __restrict__ x, const double* __restrict__ vd,
    double* __restrict__ d1, double* __restrict__ d2, float* __restrict__ absS) {
  int wave = threadIdx.x >> 6, lane = threadIdx.x & 63;
  long row0 = ((long)blockIdx.x * 4 + wave) * 4;
  const float4* xr = (const float4*)(x + row0 * H_);
  float4 x0 = xr[lane];
  float4 x1 = xr[lane + 64];
  float4 x2 = xr[lane + 128];
  float4 x3 = xr[lane + 192];
  int base = lane * 4;
  double vb0 = vd[256 + base + 0], vb1 = vd[256 + base + 1],
         vb2 = vd[256 + base + 2], vb3 = vd[256 + base + 3];
  double va0 = vd[base + 0] + vb0, va1 = vd[base + 1] + vb1,
         va2 = vd[base + 2] + vb2, va3 = vd[base + 3] + vb3;
  double p10 = (double)x0.x * va0 + (double)x0.y * va1 + (double)x0.z * va2 + (double)x0.w * va3;
  double p20 = (double)x0.x * vb0 + (double)x0.y * vb1 + (double)x0.z * vb2 + (double)x0.w * vb3;
  double p11 = (double)x1.x * va0 + (double)x1.y * va1 + (double)x1.z * va2 + (double)x1.w * va3;
  double p21 = (double)x1.x * vb0 + (double)x1.y * vb1 + (double)x1.z * vb2 + (double)x1.w * vb3;
  double p12 = (double)x2.x * va0 + (double)x2.y * va1 + (double)x2.z * va2 + (double)x2.w * va3;
  double p22 = (double)x2.x * vb0 + (double)x2.y * vb1 + (double)x2.z * vb2 + (double)x2.w * vb3;
  double p13 = (double)x3.x * va0 + (double)x3.y * va1 + (double)x3.z * va2 + (double)x3.w * va3;
  double p23 = (double)x3.x * vb0 + (double)x3.y * vb1 + (double)x3.z * vb2 + (double)x3.w * vb3;
  bool n0 = (x0.x != 0.0f) || (x0.y != 0.0f) || (x0.z != 0.0f) || (x0.w != 0.0f);
  bool n1 = (x1.x != 0.0f) || (x1.y != 0.0f) || (x1.z != 0.0f) || (x1.w != 0.0f);
  bool n2 = (x2.x != 0.0f) || (x2.y != 0.0f) || (x2.z != 0.0f) || (x2.w != 0.0f);
  bool n3 = (x3.x != 0.0f) || (x3.y != 0.0f) || (x3.z != 0.0f) || (x3.w != 0.0f);
  unsigned long long b0 = __ballot(n0), b1_ = __ballot(n1),
                     b2_ = __ballot(n2), b3 = __ballot(n3);
#pragma unroll
  for (int off = 32; off > 0; off >>= 1) {
    p10 += __shfl_xor(p10, off, 64);
    p20 += __shfl_xor(p20, off, 64);
    p11 += __shfl_xor(p11, off, 64);
    p21 += __shfl_xor(p21, off, 64);
    p12 += __shfl_xor(p12, off, 64);
    p22 += __shfl_xor(p22, off, 64);
    p13 += __shfl_xor(p13, off, 64);
    p23 += __shfl_xor(p23, off, 64);
  }
  if (lane == 0)       { d1[row0 + 0] = p10; d2[row0 + 0] = p20; absS[row0 + 0] = b0  ? 1.0f : 0.0f; }
  else if (lane == 16) { d1[row0 + 1] = p11; d2[row0 + 1] = p21; absS[row0 + 1] = b1_ ? 1.0f : 0.0f; }
  else if (lane == 32) { d1[row0 + 2] = p12; d2[row0 + 2] = p22; absS[row0 + 2] = b2_ ? 1.0f : 0.0f; }
  else if (lane == 48) { d1[row0 + 3] = p13; d2[row0 + 3] = p23; absS[row0 + 3] = b3  ? 1.0f : 0.0f; }
}

__global__ void __launch_bounds__(256) k2_weights(
    const double* __restrict__ d1, const double* __restrict__ d2,
    const float* __restrict__ absS, const float* __restrict__ mask,
    const int* __restrict__ is_tr, const double* __restrict__ c0p,
    float* __restrict__ o_ori, float* __restrict__ o_sa, float* __restrict__ o_ff,
    float* __restrict__ wsc, int* __restrict__ fireT,
    int* __restrict__ nAllArr, int* __restrict__ nUnmArr) {
  __shared__ double s_P[T_];
  __shared__ double s_tot[4];
  __shared__ double s_red[4][3];
  __shared__ double s_tot2[4];
  __shared__ double s_mtot[4];
  __shared__ int s_int[2];
  int b = blockIdx.x, tid = threadIdx.x;
  int lane = tid & 63, wv = tid >> 6;
  int t0 = tid * 8;
  const double* d1b = d1 + (long)b * T_;
  const double* d2b = d2 + (long)b * T_;
  const float* asb = absS + (long)b * T_;
  double c0 = c0p[0];
  double r2[8];
  {
    double run2 = 0.0;
#pragma unroll
    for (int k = 0; k < 8; ++k) { run2 += d2b[t0 + k]; r2[k] = run2; }
    double sc2 = run2;
#pragma unroll
    for (int off = 1; off < 64; off <<= 1) {
      double n = __shfl_up(sc2, off, 64);
      if (lane >= off) sc2 += n;
    }
    if (lane == 63) s_tot[wv] = sc2;
    __syncthreads();
    double base2 = 0.0;
    for (int i = 0; i < wv; ++i) base2 += s_tot[i];
    double e2 = base2 + (sc2 - run2);
#pragma unroll
    for (int k = 0; k < 8; ++k) s_P[t0 + k] = e2 + r2[k];
  }
  __syncthreads();
  double wd[8];
  double sa = 0.0, fpc = 0.0;
#pragma unroll
  for (int k = 0; k < 8; ++k) {
    int t = t0 + k;
    double wvv;
    if (t == 0) {
      wvv = d1b[0] - s_P[0] + c0;
    } else {
      int start = t - 10; if (start < 0) start = 0;
      double ws_ = s_P[t - 1] - (start > 0 ? s_P[start - 1] : 0.0);
      wvv = d1b[t] - ws_ / (double)(t - start) + c0;
    }
    wvv = wvv < 0.0 ? 0.0 : (wvv > 1.0 ? 1.0 : wvv);
    wd[k] = wvv;
    sa += wvv;
    fpc += (asb[t] != 0.0f) ? 1.0 : 0.0;
  }
  {
    float4* ov = (float4*)(o_ori + (long)b * T_ + t0);
    ov[0] = make_float4((float)wd[0], (float)wd[1], (float)wd[2], (float)wd[3]);
    ov[1] = make_float4((float)wd[4], (float)wd[5], (float)wd[6], (float)wd[7]);
  }
  double ms = (tid < 200) ? (double)mask[(long)b * 200 + tid] : 0.0;
  double sar = waveReduceD(sa), fpr = waveReduceD(fpc), msr = waveReduceD(ms);
  if (lane == 0) { s_red[wv][0] = sar; s_red[wv][1] = fpr; s_red[wv][2] = msr; }
  __syncthreads();
  double sumA = s_red[0][0] + s_red[1][0] + s_red[2][0] + s_red[3][0];
  double fpD  = s_red[0][1] + s_red[1][1] + s_red[2][1] + s_red[3][1];
  double maskSum = s_red[0][2] + s_red[1][2] + s_red[2][2] + s_red[3][2];
  if (tid == 0) o_sa[b] = (float)sumA;
  int firstPad = (int)(fpD + 0.5);
  double scale;
  if (is_tr[0] != 0) {
    scale = (sumA == 0.0) ? 0.0 : (maskSum - 1.0) / (sumA > 1e-8 ? sumA : 1e-8);
  } else {
    scale = 1.0;
  }
  double a[8], r[8];
  double run = 0.0;
#pragma unroll
  for (int k = 0; k < 8; ++k) {
    int t = t0 + k;
    double av = wd[k] * scale;
    if (t > firstPad) av = 0.0;
    a[k] = av;
    run += av; r[k] = run;
  }
  {
    float4* wvv = (float4*)(wsc + (long)b * T_ + t0);
    wvv[0] = make_float4((float)a[0], (float)a[1], (float)a[2], (float)a[3]);
    wvv[1] = make_float4((float)a[4], (float)a[5], (float)a[6], (float)a[7]);
  }
  double sc = run;
#pragma unroll
  for (int off = 1; off < 64; off <<= 1) {
    double n = __shfl_up(sc, off, 64);
    if (lane >= off) sc += n;
  }
  if (lane == 63) s_tot2[wv] = sc;
  __syncthreads();
  double base = 0.0;
  for (int i = 0; i < wv; ++i) base += s_tot2[i];
  double e = base + (sc - run);
  double m[8];
  double mn = 1e300;
#pragma unroll
  for (int k = 0; k < 8; ++k) {
    double S = e + r[k];
    double kp = ceil(S - 1.0); if (kp < 0.0) kp = 0.0;
    double D = kp - (double)(t0 + k);
    mn = fmin(mn, D);
    m[k] = mn;
  }
  double scm = mn;
#pragma unroll
  for (int off = 1; off < 64; off <<= 1) {
    double n = __shfl_up(scm, off, 64);
    if (lane >= off) scm = fmin(scm, n);
  }
  double exw = __shfl_up(scm, 1, 64);
  if (lane == 0) exw = 1e300;
  if (lane == 63) s_mtot[wv] = scm;
  __syncthreads();
  double mbase = 1e300;
  for (int i = 0; i < wv; ++i) mbase = fmin(mbase, s_mtot[i]);
  double Mexcl = fmin(mbase, exw);
  float flags[8];
  int Cp = (t0 - 1) + (int)fmin(1.0, Mexcl);
#pragma unroll
  for (int k = 0; k < 8; ++k) {
    int t = t0 + k;
    double Mk = fmin(Mexcl, m[k]);
    int C = t + (int)fmin(1.0, Mk);
    bool fired = C > Cp;
    flags[k] = fired ? 1.0f : 0.0f;
    if (fired) fireT[(long)b * T_ + (C - 1)] = t;
    if (t == firstPad) s_int[0] = C;
    Cp = C;
  }
  {
    float4* fv = (float4*)(o_ff + (long)b * T_ + t0);
    fv[0] = make_float4(flags[0], flags[1], flags[2], flags[3]);
    fv[1] = make_float4(flags[4], flags[5], flags[6], flags[7]);
  }
  if (tid == 255) s_int[1] = Cp;
  __syncthreads();
  if (tid == 0) {
    int nA = s_int[1];
    nAllArr[b] = nA;
    nUnmArr[b] = (firstPad >= T_) ? nA : s_int[0];
  }
}

__global__ void __launch_bounds__(256) k4_rows(
    const float* __restrict__ x, const float* __restrict__ wsc,
    const int* __restrict__ fireT,
    const int* __restrict__ nAllArr, const int* __restrict__ nUnmArr,
    float* __restrict__ cif, float* __restrict__ notpad) {
  int wave = threadIdx.x >> 6, lane = threadIdx.x & 63;
  int pos = blockIdx.x * 4 + wave;
  int b = blockIdx.y;
  if (pos >= L_) return;
  int nA = nAllArr[b], nU = nUnmArr[b];
  float* crow = cif + ((long)b * L_ + pos) * H_ + lane * 4;
  if (pos > nU) {
    nt_store4(make_float4(0.0f, 0.0f, 0.0f, 0.0f), crow);
    if (lane == 0) notpad[(long)b * L_ + pos] = 0.0f;
    return;
  }
  const int* ftb = fireT + (long)b * T_;
  int hi, anchor, lo;
  if (pos < nU) {
    hi = ftb[pos];
    anchor = (pos == 0) ? 0 : ftb[pos - 1];
    lo = (pos == 0) ? 0 : anchor + 1;
  } else {
    hi = T_ - 1;
    anchor = (nA == 0) ? 0 : ftb[nA - 1];
    lo = (nA == 0) ? 0 : anchor + 1;
  }
  const float* xb = x + (long)b * T_ * H_;
  float4 acc = ((const float4*)(xb + (long)anchor * H_))[lane];
  float4 acc2 = make_float4(0.0f, 0.0f, 0.0f, 0.0f);
  const float* wb = wsc + (long)b * T_;
  int u = lo;
  for (; u + 1 <= hi; u += 2) {
    float f0 = 1.0f - wb[u];
    float f1 = 1.0f - wb[u + 1];
    float4 xv0 = ((const float4*)(xb + (long)u * H_))[lane];
    float4 xv1 = ((const float4*)(xb + (long)(u + 1) * H_))[lane];
    acc.x += f0 * xv0.x;  acc.y += f0 * xv0.y;
    acc.z += f0 * xv0.z;  acc.w += f0 * xv0.w;
    acc2.x += f1 * xv1.x; acc2.y += f1 * xv1.y;
    acc2.z += f1 * xv1.z; acc2.w += f1 * xv1.w;
  }
  if (u <= hi) {
    float f = 1.0f - wb[u];
    float4 xv = ((const float4*)(xb + (long)u * H_))[lane];
    acc.x += f * xv.x; acc.y += f * xv.y; acc.z += f * xv.z; acc.w += f * xv.w;
  }
  acc.x += acc2.x; acc.y += acc2.y; acc.z += acc2.z; acc.w += acc2.w;
  float ss = acc.x * acc.x + acc.y * acc.y + acc.z * acc.z + acc.w * acc.w;
#pragma unroll
  for (int off = 32; off > 0; off >>= 1) ss += __shfl_xor(ss, off, 64);
  float inv = 1.0f / fmaxf(sqrtf(ss), 1e-12f);
  nt_store4(make_float4(acc.x * inv, acc.y * inv, acc.z * inv, acc.w * inv), crow);
  if (lane == 0) notpad[(long)b * L_ + pos] = 1.0f;
}

// ---------------- launch ----------------
extern "C" void kernel_launch(void* const* d_in, const int* in_sizes, int n_in,
                              void* d_out, int out_size, void* d_ws, size_t ws_size,
                              hipStream_t stream) {
  const float* x    = (const float*)d_in[0];
  const float* mask = (const float*)d_in[1];
  const float* W1   = (const float*)d_in[2];
  const float* b1   = (const float*)d_in[3];
  const float* W2   = (const float*)d_in[4];
  const float* b2   = (const float*)d_in[5];
  const int*   istr = (const int*)d_in[6];

  float* out = (float*)d_out;
  float* o_cif = out;                                  // B*L*H
  float* o_ori = o_cif + (size_t)B_ * L_ * H_;         // B*T
  float* o_ff  = o_ori + (size_t)B_ * T_;              // B*T
  float* o_np  = o_ff  + (size_t)B_ * T_;              // B*L
  float* o_sa  = o_np  + (size_t)B_ * L_;              // B

  char* w = (char*)d_ws;
  int* bar     = (int*)w;    w += 3 * 32 * 4;          // padded barrier counters
  double* vd   = (double*)w; w += 512 * 8;
  double* c0   = (double*)w; w += 8;
  double* d1   = (double*)w; w += (size_t)B_ * T_ * 8;
  double* d2   = (double*)w; w += (size_t)B_ * T_ * 8;
  float* absS  = (float*)w;  w += (size_t)B_ * T_ * 4;
  float* wsc   = (float*)w;  w += (size_t)B_ * T_ * 4;
  int* fireT   = (int*)w;    w += (size_t)B_ * T_ * 4;
  int* nAllA   = (int*)w;    w += B_ * 4;
  int* nUnmA   = (int*)w;    w += B_ * 4;

  // resident-grid sizing: need all blocks co-resident for the grid barrier.
  static int s_grid = -1;
  if (s_grid < 0) {
    int nb = 0;
    hipError_t e = hipOccupancyMaxActiveBlocksPerMultiprocessor(
        &nb, (const void*)k_fused, 256, 0);
    if (e == hipSuccess && nb >= 1) {
      long g = (long)nb * 256;     // 256 CUs on MI355X
      if (g > 1024) g = 1024;
      s_grid = (int)g;
    } else {
      s_grid = 0;
    }
  }

  if (s_grid >= 64) {
    hipMemsetAsync(bar, 0, 3 * 32 * 4, stream);
    k_fused<<<s_grid, 256, 0, stream>>>(
        x, mask, W1, b1, W2, b2, istr,
        o_cif, o_ori, o_ff, o_np, o_sa,
        vd, c0, d1, d2, absS, wsc, fireT, nAllA, nUnmA, bar);
  } else {
    // fallback: verified 4-kernel pipeline
    k0_fold<<<16, 256, 0, stream>>>(W1, b1, W2, b2, vd, c0);
    k1_rowdots<<<(B_ * T_) / 16, 256, 0, stream>>>(x, vd, d1, d2, absS);
    k2_weights<<<B_, 256, 0, stream>>>(d1, d2, absS, mask, istr, c0,
                                       o_ori, o_sa, o_ff, wsc, fireT,
                                       nAllA, nUnmA);
    k4_rows<<<dim3((L_ + 3) / 4, B_), 256, 0, stream>>>(
        x, wsc, fireT, nAllA, nUnmA, o_cif, o_np);
  }
}

// Round 5
// 146.399 us; speedup vs baseline: 2.4474x; 2.4474x over previous
//
#include <hip/hip_runtime.h>

#define B_ 32
#define T_ 2048
#define H_ 256
#define L_ 2049   // T_ + 1

// zero-fill split point: rows pos >= ZCUT are provably zero when is_training
// (S_total <= maskSum-1 <= 199  =>  nA <= ~199 << ZCUT), so they are filled
// during k1 (overlapping with its DS-bound reduction) instead of in k4.
// k4 keeps a dynamic fallback (writes them itself if nU >= ZCUT) so the
// kernel stays correct for arbitrary data.
#define ZCUT 512
#define ZROWS (L_ - ZCUT)            // 1537 zero rows per batch
#define K1_DOT_BLOCKS ((B_ * T_) / 16)               // 4096
#define K1_Z_BLOCKS   ((B_ * ZROWS + 15) / 16)       // 3074 (16 rows/block)

// ---------------- helpers ----------------
__device__ inline double waveReduceD(double v) {
#pragma unroll
  for (int off = 32; off > 0; off >>= 1) v += __shfl_xor(v, off, 64);
  return v;
}

typedef float vfloat4 __attribute__((ext_vector_type(4)));
__device__ inline void nt_store4(float4 v, float* p) {
  vfloat4 t;
  t.x = v.x; t.y = v.y; t.z = v.z; t.w = v.w;
  __builtin_nontemporal_store(t, (vfloat4*)p);
}

// ---------------- K0: fold the two linear layers (32 blocks) ----------------
// v[c] = sum_o W2[o] * W1[o,c]  (c in [0,512)),  c0 = W2.b1 + b2
// 32 blocks x 16 cols each (16-wide 64B coalesced segments), 16 o-slices of
// 32 rows -> halves the latency-bound tail vs the 16-block version.
__global__ void __launch_bounds__(256) k0_fold(
    const float* __restrict__ W1, const float* __restrict__ b1,
    const float* __restrict__ W2, const float* __restrict__ b2,
    double* __restrict__ vd, double* __restrict__ c0) {
  __shared__ double s_p[16][17];    // +1 pad: doubles, avoid bank aliasing
  int tid = threadIdx.x;
  int cl = tid & 15, sl = tid >> 4;         // 16 cols x 16 slices
  int c = blockIdx.x * 16 + cl;
  double acc = 0.0;
#pragma unroll 8
  for (int o = sl * 32; o < sl * 32 + 32; ++o)
    acc += (double)W2[o] * (double)W1[o * 512 + c];
  s_p[sl][cl] = acc;
  __syncthreads();
  if (sl == 0) {
    double v = 0.0;
#pragma unroll
    for (int i = 0; i < 16; ++i) v += s_p[i][cl];
    vd[c] = v;
  }
  if (blockIdx.x == 0) {
    __shared__ double red[256];
    double p = (double)W2[tid] * (double)b1[tid] +
               (double)W2[tid + 256] * (double)b1[tid + 256];
    red[tid] = p;
    __syncthreads();
    for (int s = 128; s > 0; s >>= 1) {
      if (tid < s) red[tid] += red[tid + s];
      __syncthreads();
    }
    if (tid == 0) c0[0] = red[0] + (double)b2[0];
  }
}

// ---------------- K1: row dots (blocks < K1_DOT_BLOCKS) + zero-fill tail --
// dots: d1[r] = x_row.(v1+v2), d2[r] = x_row.v2, absS[r] = any-nonzero
// tail: when is_training, zero cif rows pos in [ZCUT, L) + their notpad.
__global__ void __launch_bounds__(256) k1_rowdots(
    const float* __restrict__ x, const double* __restrict__ vd,
    const int* __restrict__ is_tr,
    double* __restrict__ d1, double* __restrict__ d2, float* __restrict__ absS,
    float* __restrict__ cif, float* __restrict__ notpad) {
  int wave = threadIdx.x >> 6, lane = threadIdx.x & 63;
  if (blockIdx.x >= K1_DOT_BLOCKS) {
    // ---- zero-fill portion: 16 rows per block (4 per wave) ----
    if (is_tr[0] == 0) return;       // !training: k4 covers everything
    int idx = blockIdx.x - K1_DOT_BLOCKS;
    int zr0 = idx * 16 + wave * 4;
#pragma unroll
    for (int k = 0; k < 4; ++k) {
      int zr = zr0 + k;              // 0 .. B_*ZROWS-1 (exact multiple of 16)
      int b = zr / ZROWS, pos = ZCUT + (zr - b * ZROWS);
      float* crow = cif + ((long)b * L_ + pos) * H_ + lane * 4;
      nt_store4(make_float4(0.0f, 0.0f, 0.0f, 0.0f), crow);
      if (lane == 0) notpad[(long)b * L_ + pos] = 0.0f;
    }
    return;
  }
  long row0 = ((long)blockIdx.x * 4 + wave) * 4;  // 4 consecutive rows
  const float4* xr = (const float4*)(x + row0 * H_);
  float4 x0 = xr[lane];
  float4 x1 = xr[lane + 64];
  float4 x2 = xr[lane + 128];
  float4 x3 = xr[lane + 192];
  int base = lane * 4;
  double vb0 = vd[256 + base + 0], vb1 = vd[256 + base + 1],
         vb2 = vd[256 + base + 2], vb3 = vd[256 + base + 3];
  double va0 = vd[base + 0] + vb0, va1 = vd[base + 1] + vb1,
         va2 = vd[base + 2] + vb2, va3 = vd[base + 3] + vb3;
  double p10 = (double)x0.x * va0 + (double)x0.y * va1 + (double)x0.z * va2 + (double)x0.w * va3;
  double p20 = (double)x0.x * vb0 + (double)x0.y * vb1 + (double)x0.z * vb2 + (double)x0.w * vb3;
  double p11 = (double)x1.x * va0 + (double)x1.y * va1 + (double)x1.z * va2 + (double)x1.w * va3;
  double p21 = (double)x1.x * vb0 + (double)x1.y * vb1 + (double)x1.z * vb2 + (double)x1.w * vb3;
  double p12 = (double)x2.x * va0 + (double)x2.y * va1 + (double)x2.z * va2 + (double)x2.w * va3;
  double p22 = (double)x2.x * vb0 + (double)x2.y * vb1 + (double)x2.z * vb2 + (double)x2.w * vb3;
  double p13 = (double)x3.x * va0 + (double)x3.y * va1 + (double)x3.z * va2 + (double)x3.w * va3;
  double p23 = (double)x3.x * vb0 + (double)x3.y * vb1 + (double)x3.z * vb2 + (double)x3.w * vb3;
  bool n0 = (x0.x != 0.0f) || (x0.y != 0.0f) || (x0.z != 0.0f) || (x0.w != 0.0f);
  bool n1 = (x1.x != 0.0f) || (x1.y != 0.0f) || (x1.z != 0.0f) || (x1.w != 0.0f);
  bool n2 = (x2.x != 0.0f) || (x2.y != 0.0f) || (x2.z != 0.0f) || (x2.w != 0.0f);
  bool n3 = (x3.x != 0.0f) || (x3.y != 0.0f) || (x3.z != 0.0f) || (x3.w != 0.0f);
  unsigned long long b0 = __ballot(n0), b1_ = __ballot(n1),
                     b2_ = __ballot(n2), b3 = __ballot(n3);
  // 8 interleaved butterflies — independent chains hide ds latency
#pragma unroll
  for (int off = 32; off > 0; off >>= 1) {
    p10 += __shfl_xor(p10, off, 64);
    p20 += __shfl_xor(p20, off, 64);
    p11 += __shfl_xor(p11, off, 64);
    p21 += __shfl_xor(p21, off, 64);
    p12 += __shfl_xor(p12, off, 64);
    p22 += __shfl_xor(p22, off, 64);
    p13 += __shfl_xor(p13, off, 64);
    p23 += __shfl_xor(p23, off, 64);
  }
  if (lane == 0)       { d1[row0 + 0] = p10; d2[row0 + 0] = p20; absS[row0 + 0] = b0  ? 1.0f : 0.0f; }
  else if (lane == 16) { d1[row0 + 1] = p11; d2[row0 + 1] = p21; absS[row0 + 1] = b1_ ? 1.0f : 0.0f; }
  else if (lane == 32) { d1[row0 + 2] = p12; d2[row0 + 2] = p22; absS[row0 + 2] = b2_ ? 1.0f : 0.0f; }
  else if (lane == 48) { d1[row0 + 3] = p13; d2[row0 + 3] = p23; absS[row0 + 3] = b3  ? 1.0f : 0.0f; }
}

// ---------------- K2: weights + EXACT parallel fire solve (1 block / b) --
// prev_t = S_t - C_t identically, so C_t = min(C_{t-1}+1, Kp_t) with
// Kp_t = max(0, ceil(S_t - 1)) nondecreasing. Exact solution:
//   C_t = t + min(1, M_t),  M_t = min_{s<=t}(Kp_s - s).   (any a_t >= 0)
__global__ void __launch_bounds__(256) k2_weights(
    const double* __restrict__ d1, const double* __restrict__ d2,
    const float* __restrict__ absS, const float* __restrict__ mask,
    const int* __restrict__ is_tr, const double* __restrict__ c0p,
    float* __restrict__ o_ori, float* __restrict__ o_sa, float* __restrict__ o_ff,
    float* __restrict__ wsc, int* __restrict__ fireT,
    int* __restrict__ nAllArr, int* __restrict__ nUnmArr) {
  __shared__ double s_P[T_];        // prefix sums of d2 (16 KB)
  __shared__ double s_tot[4];       // wave totals (cumsum #1)
  __shared__ double s_red[4][3];    // wave partials: sumA, fpc, maskSum
  __shared__ double s_tot2[4];      // wave totals (cumsum #2)
  __shared__ double s_mtot[4];      // wave mins (min-scan)
  __shared__ int s_int[2];          // [0]=C@firstPad, [1]=nA
  int b = blockIdx.x, tid = threadIdx.x;
  int lane = tid & 63, wv = tid >> 6;
  int t0 = tid * 8;                 // 8 contiguous elements per thread
  const double* d1b = d1 + (long)b * T_;
  const double* d2b = d2 + (long)b * T_;
  const float* asb = absS + (long)b * T_;
  double c0 = c0p[0];

  // ---- prefix sum of d2 -> s_P ----
  double r2[8];
  {
    double run2 = 0.0;
#pragma unroll
    for (int k = 0; k < 8; ++k) { run2 += d2b[t0 + k]; r2[k] = run2; }
    double sc2 = run2;
#pragma unroll
    for (int off = 1; off < 64; off <<= 1) {
      double n = __shfl_up(sc2, off, 64);
      if (lane >= off) sc2 += n;
    }
    if (lane == 63) s_tot[wv] = sc2;
    __syncthreads();
    double base2 = 0.0;
    for (int i = 0; i < wv; ++i) base2 += s_tot[i];
    double e2 = base2 + (sc2 - run2);
#pragma unroll
    for (int k = 0; k < 8; ++k) s_P[t0 + k] = e2 + r2[k];
  }
  __syncthreads();

  // ---- Part A: w = clip(relu(d1 - windowmean + c0), 0, 1); windowsum via P
  double wd[8];
  double sa = 0.0, fpc = 0.0;
#pragma unroll
  for (int k = 0; k < 8; ++k) {
    int t = t0 + k;
    double wvv;
    if (t == 0) {
      wvv = d1b[0] - s_P[0] + c0;  // hist[0] = x[0]
    } else {
      int start = t - 10; if (start < 0) start = 0;
      double ws_ = s_P[t - 1] - (start > 0 ? s_P[start - 1] : 0.0);
      wvv = d1b[t] - ws_ / (double)(t - start) + c0;
    }
    wvv = wvv < 0.0 ? 0.0 : (wvv > 1.0 ? 1.0 : wvv);
    wd[k] = wvv;
    sa += wvv;
    fpc += (asb[t] != 0.0f) ? 1.0 : 0.0;
  }
  {  // o_ori: two float4 stores (contiguous 8)
    float4* ov = (float4*)(o_ori + (long)b * T_ + t0);
    ov[0] = make_float4((float)wd[0], (float)wd[1], (float)wd[2], (float)wd[3]);
    ov[1] = make_float4((float)wd[4], (float)wd[5], (float)wd[6], (float)wd[7]);
  }
  // ---- reductions via wave shuffles (sumA, firstPad count, maskSum)
  double ms = (tid < 200) ? (double)mask[(long)b * 200 + tid] : 0.0;
  double sar = waveReduceD(sa), fpr = waveReduceD(fpc), msr = waveReduceD(ms);
  if (lane == 0) { s_red[wv][0] = sar; s_red[wv][1] = fpr; s_red[wv][2] = msr; }
  __syncthreads();
  double sumA = s_red[0][0] + s_red[1][0] + s_red[2][0] + s_red[3][0];
  double fpD  = s_red[0][1] + s_red[1][1] + s_red[2][1] + s_red[3][1];
  double maskSum = s_red[0][2] + s_red[1][2] + s_red[2][2] + s_red[3][2];
  if (tid == 0) o_sa[b] = (float)sumA;
  int firstPad = (int)(fpD + 0.5);
  double scale;
  if (is_tr[0] != 0) {
    scale = (sumA == 0.0) ? 0.0 : (maskSum - 1.0) / (sumA > 1e-8 ? sumA : 1e-8);
  } else {
    scale = 1.0;
  }

  // ---- scaled + pad-masked a; write wsc; cumsum -> S_t
  double a[8], r[8];
  double run = 0.0;
#pragma unroll
  for (int k = 0; k < 8; ++k) {
    int t = t0 + k;
    double av = wd[k] * scale;
    if (t > firstPad) av = 0.0;
    a[k] = av;
    run += av; r[k] = run;
  }
  {  // wsc: two float4 stores
    float4* wvv = (float4*)(wsc + (long)b * T_ + t0);
    wvv[0] = make_float4((float)a[0], (float)a[1], (float)a[2], (float)a[3]);
    wvv[1] = make_float4((float)a[4], (float)a[5], (float)a[6], (float)a[7]);
  }
  double sc = run;
#pragma unroll
  for (int off = 1; off < 64; off <<= 1) {
    double n = __shfl_up(sc, off, 64);
    if (lane >= off) sc += n;
  }
  if (lane == 63) s_tot2[wv] = sc;
  __syncthreads();
  double base = 0.0;
  for (int i = 0; i < wv; ++i) base += s_tot2[i];
  double e = base + (sc - run);  // exclusive prefix for this thread

  // ---- D_t = Kp_t - t, prefix-min scan -> M_t, C_t = t + min(1, M_t)
  double m[8];
  double mn = 1e300;
#pragma unroll
  for (int k = 0; k < 8; ++k) {
    double S = e + r[k];
    double kp = ceil(S - 1.0); if (kp < 0.0) kp = 0.0;
    double D = kp - (double)(t0 + k);
    mn = fmin(mn, D);
    m[k] = mn;
  }
  double scm = mn;
#pragma unroll
  for (int off = 1; off < 64; off <<= 1) {
    double n = __shfl_up(scm, off, 64);
    if (lane >= off) scm = fmin(scm, n);
  }
  double exw = __shfl_up(scm, 1, 64);       // wave-exclusive inclusive-min
  if (lane == 0) exw = 1e300;
  if (lane == 63) s_mtot[wv] = scm;
  __syncthreads();
  double mbase = 1e300;
  for (int i = 0; i < wv; ++i) mbase = fmin(mbase, s_mtot[i]);
  double Mexcl = fmin(mbase, exw);          // min over s < t0

  // ---- fires ----
  float flags[8];
  int Cp = (t0 - 1) + (int)fmin(1.0, Mexcl);  // t0==0: Mexcl=inf -> C_{-1}=0
#pragma unroll
  for (int k = 0; k < 8; ++k) {
    int t = t0 + k;
    double Mk = fmin(Mexcl, m[k]);
    int C = t + (int)fmin(1.0, Mk);
    bool fired = C > Cp;
    flags[k] = fired ? 1.0f : 0.0f;
    if (fired) fireT[(long)b * T_ + (C - 1)] = t;
    if (t == firstPad) s_int[0] = C;
    Cp = C;
  }
  {  // o_ff: two float4 stores
    float4* fv = (float4*)(o_ff + (long)b * T_ + t0);
    fv[0] = make_float4(flags[0], flags[1], flags[2], flags[3]);
    fv[1] = make_float4(flags[4], flags[5], flags[6], flags[7]);
  }
  if (tid == 255) s_int[1] = Cp;  // nA = C_{T-1}
  __syncthreads();
  if (tid == 0) {
    int nA = s_int[1];
    nAllArr[b] = nA;
    nUnmArr[b] = (firstPad >= T_) ? nA : s_int[0];
  }
}

// ---------------- K4: cif rows (work rows + remaining zero rows) ----------
// grid (ceil(L/4), B), 256 threads = 4 waves, one pos per wave.
// Rows pos >= ZCUT with pos > nU were already zero-filled during k1 when
// is_training != 0; skip their stores here. Everything else as before.
__global__ void __launch_bounds__(256) k4_rows(
    const float* __restrict__ x, const float* __restrict__ wsc,
    const int* __restrict__ fireT,
    const int* __restrict__ nAllArr, const int* __restrict__ nUnmArr,
    const int* __restrict__ is_tr,
    float* __restrict__ cif, float* __restrict__ notpad) {
  int wave = threadIdx.x >> 6, lane = threadIdx.x & 63;
  int pos = blockIdx.x * 4 + wave;
  int b = blockIdx.y;
  if (pos >= L_) return;
  int nA = nAllArr[b], nU = nUnmArr[b];
  float* crow = cif + ((long)b * L_ + pos) * H_ + lane * 4;
  if (pos > nU) {
    if (pos >= ZCUT && is_tr[0] != 0) return;   // pre-zeroed in k1
    nt_store4(make_float4(0.0f, 0.0f, 0.0f, 0.0f), crow);
    if (lane == 0) notpad[(long)b * L_ + pos] = 0.0f;
    return;
  }
  const int* ftb = fireT + (long)b * T_;
  int hi, anchor, lo;
  if (pos < nU) {
    hi = ftb[pos];
    anchor = (pos == 0) ? 0 : ftb[pos - 1];
    lo = (pos == 0) ? 0 : anchor + 1;
  } else {
    hi = T_ - 1;                       // final carry state fin_s
    anchor = (nA == 0) ? 0 : ftb[nA - 1];
    lo = (nA == 0) ? 0 : anchor + 1;
  }
  const float* xb = x + (long)b * T_ * H_;
  float4 acc = ((const float4*)(xb + (long)anchor * H_))[lane];
  float4 acc2 = make_float4(0.0f, 0.0f, 0.0f, 0.0f);
  const float* wb = wsc + (long)b * T_;
  int u = lo;
  for (; u + 1 <= hi; u += 2) {   // dual accumulators: half the dep chain
    float f0 = 1.0f - wb[u];
    float f1 = 1.0f - wb[u + 1];
    float4 xv0 = ((const float4*)(xb + (long)u * H_))[lane];
    float4 xv1 = ((const float4*)(xb + (long)(u + 1) * H_))[lane];
    acc.x += f0 * xv0.x;  acc.y += f0 * xv0.y;
    acc.z += f0 * xv0.z;  acc.w += f0 * xv0.w;
    acc2.x += f1 * xv1.x; acc2.y += f1 * xv1.y;
    acc2.z += f1 * xv1.z; acc2.w += f1 * xv1.w;
  }
  if (u <= hi) {
    float f = 1.0f - wb[u];
    float4 xv = ((const float4*)(xb + (long)u * H_))[lane];
    acc.x += f * xv.x; acc.y += f * xv.y; acc.z += f * xv.z; acc.w += f * xv.w;
  }
  acc.x += acc2.x; acc.y += acc2.y; acc.z += acc2.z; acc.w += acc2.w;
  float ss = acc.x * acc.x + acc.y * acc.y + acc.z * acc.z + acc.w * acc.w;
#pragma unroll
  for (int off = 32; off > 0; off >>= 1) ss += __shfl_xor(ss, off, 64);
  float inv = 1.0f / fmaxf(sqrtf(ss), 1e-12f);
  nt_store4(make_float4(acc.x * inv, acc.y * inv, acc.z * inv, acc.w * inv), crow);
  if (lane == 0) notpad[(long)b * L_ + pos] = 1.0f;
}

// ---------------- launch ----------------
extern "C" void kernel_launch(void* const* d_in, const int* in_sizes, int n_in,
                              void* d_out, int out_size, void* d_ws, size_t ws_size,
                              hipStream_t stream) {
  const float* x    = (const float*)d_in[0];
  const float* mask = (const float*)d_in[1];
  const float* W1   = (const float*)d_in[2];
  const float* b1   = (const float*)d_in[3];
  const float* W2   = (const float*)d_in[4];
  const float* b2   = (const float*)d_in[5];
  const int*   istr = (const int*)d_in[6];

  float* out = (float*)d_out;
  // output layout (all fp32, concatenated in return order)
  float* o_cif = out;                                  // B*L*H
  float* o_ori = o_cif + (size_t)B_ * L_ * H_;         // B*T
  float* o_ff  = o_ori + (size_t)B_ * T_;              // B*T
  float* o_np  = o_ff  + (size_t)B_ * T_;              // B*L
  float* o_sa  = o_np  + (size_t)B_ * L_;              // B

  // workspace layout
  char* w = (char*)d_ws;
  double* vd   = (double*)w; w += 512 * 8;
  double* c0   = (double*)w; w += 8;
  double* d1   = (double*)w; w += (size_t)B_ * T_ * 8;
  double* d2   = (double*)w; w += (size_t)B_ * T_ * 8;
  float* absS  = (float*)w;  w += (size_t)B_ * T_ * 4;
  float* wsc   = (float*)w;  w += (size_t)B_ * T_ * 4;
  int* fireT   = (int*)w;    w += (size_t)B_ * T_ * 4;
  int* nAllA   = (int*)w;    w += B_ * 4;
  int* nUnmA   = (int*)w;    w += B_ * 4;

  // no memset: k2 covers o_ori/o_ff/o_sa; k1-tail + k4 cover cif + o_np.
  k0_fold<<<32, 256, 0, stream>>>(W1, b1, W2, b2, vd, c0);
  k1_rowdots<<<K1_DOT_BLOCKS + K1_Z_BLOCKS, 256, 0, stream>>>(
      x, vd, istr, d1, d2, absS, o_cif, o_np);
  k2_weights<<<B_, 256, 0, stream>>>(d1, d2, absS, mask, istr, c0,
                                     o_ori, o_sa, o_ff, wsc, fireT,
                                     nAllA, nUnmA);
  k4_rows<<<dim3((L_ + 3) / 4, B_), 256, 0, stream>>>(
      x, wsc, fireT, nAllA, nUnmA, istr, o_cif, o_np);
}